// Round 10
// baseline (644.867 us; speedup 1.0000x reference)
//
#include <hip/hip_runtime.h>
#include <math.h>

#define CIN   16
#define DDEP  8      // conv depth (routing "D")
#define HIN   96
#define WIN   96
#define HOUT  94
#define WOUT  94
#define HW    (HOUT*WOUT)        // 8836
#define CH    256                 // out channels = c*8+d
#define DCAP  8
#define KTOT  (CIN*9)             // 144
#define KTILES 5                  // K padded to 160
#define APAD  168                 // A row stride (bf16 elems)
#define EPSQ  1e-8f

#define B_ELEMS ((size_t)8*DDEP*DCAP*HW)          // 4,524,032 floats
#define WFRAG_ELEMS ((size_t)KTILES*16*64*8)      // 40,960 per half
#define BLK_PER_B (94*12)                         // 1128 spatial blocks/batch
#define VSITES (DCAP*HW)                          // 70,688 sites per batch
#define NBLK2  277                                // ceil(70688/256)
#define XN ((size_t)8*CIN*DDEP*HIN*WIN)           // 9,437,184 x elems
#define XBLK  9216                                // XN/4/256 exactly
#define G_BYTES ((size_t)8*VSITES*36*4)           // 81,432,576 B

typedef __attribute__((ext_vector_type(8))) short bf16x8;
typedef __attribute__((ext_vector_type(4))) float f32x4;

// explicit RNE float->bf16 bit conversion
__device__ __forceinline__ ushort f2bf(float f) {
    unsigned u = __float_as_uint(f);
    return (ushort)((u + 0x7FFFu + ((u >> 16) & 1u)) >> 16);
}
__device__ __forceinline__ float bf2f(ushort h) {
    return __uint_as_float(((unsigned)h) << 16);
}

// ---------------------------------------------------------------------------
// r19 prep: fused (a) x -> bf16 side-cache (blocks 0..9215) and (b) W -> MFMA
// B-fragment hi/lo split (blocks 9216..9295; frag[kt][nt][lane][j] = W[k][n],
// k = kt*32+(lane>>4)*8+j (0 for k>=144), n = nt*16+(lane&15)).
// ---------------------------------------------------------------------------
__global__ __launch_bounds__(256) void prep(
    const float* __restrict__ x, ushort* __restrict__ xb,
    const float* __restrict__ w, ushort* __restrict__ w_hi, ushort* __restrict__ w_lo)
{
    const int bid = blockIdx.x;
    if (bid < XBLK) {
        size_t i = (size_t)bid*256 + threadIdx.x;
        float4 v = ((const float4*)x)[i];
        ushort4 o;
        o.x = f2bf(v.x); o.y = f2bf(v.y); o.z = f2bf(v.z); o.w = f2bf(v.w);
        ((ushort4*)xb)[i] = o;
    } else if (threadIdx.x < 64) {
        const int b2 = bid - XBLK;
        const int nt = b2 & 15, kt = b2 >> 4;
        const int lane = threadIdx.x;
        const int n  = nt*16 + (lane & 15);
        const int kb = kt*32 + (lane >> 4)*8;
        size_t off = (((size_t)kt*16 + nt)*64 + lane)*8;
        for (int j = 0; j < 8; ++j) {
            int k = kb + j;
            float v = (k < KTOT) ? w[(size_t)n*KTOT + k] : 0.f;
            ushort hi = f2bf(v);
            float  r  = v - bf2f(hi);
            ushort lo = f2bf(r);
            w_hi[off + j] = hi; w_lo[off + j] = lo;
        }
    }
}

// ---------------------------------------------------------------------------
// Pass A (r19): conv + Gram write + iter1-from-G (b1 + Z1 partials).
// Block: (wx,h0,bb) -> 8 D x 1 h-row x 8 w; M=64, N=256.
// acc[mt][nt][r]: m = mt*16 + quad*4 + r -> D = mt*2 + (quad>>1),
//                 wi = (quad&1)*4 + r;  ch = wv*64 + nt*16 + m16.
// GW core: VERBATIM r12 form (per-r barrier loop, Dq==rq half-lane guard) —
// r17/r18 measured no-spill (WRITE = exactly expected bytes). r13/r14 lesson:
// the all-lane 2-r-batched GW rewrite spilled ~130 regs/thread (1.2GB writes,
// 3x slower); the per-r barriers/guards bound liveness. DO NOT restructure
// the G36 accumulation. Keep __launch_bounds__(256,2).
// r19 addition: after each r's Gm write, 16 threads compute iter1 b1 for the
// 16 sites of that r from the SAME gst sums (bit-identical g to what Gm gets;
// arithmetic copied verbatim from gram_route<1>, validated r13/r14). G36 is
// dead in that region -> no liveness growth.
// Spill tripwire: WRITE_SIZE must be ~100 MB (G 81.4 + b 18 + Zp).
// ---------------------------------------------------------------------------
__global__ __launch_bounds__(256, 2) void conv_g(
    const ushort* __restrict__ xb,
    const ushort* __restrict__ w_hi, const ushort* __restrict__ w_lo,
    float* __restrict__ bws, float* __restrict__ Zp1, float* __restrict__ Gm)
{
    const int t  = threadIdx.x;
    const int wx = blockIdx.x, h0 = blockIdx.y, bb = blockIdx.z;
    const int w0 = wx*8;

    __shared__ __align__(16) ushort a_hi[64][APAD];  // 21504 B (all phases)
    __shared__ union {                               // 9216 B, lifetime-disjoint
        ushort patchb[CIN][DDEP][3][10];             //   phases 0-1 (7680 B)
        float gst[4][16][36];                        //   Gram staging (post-MFMA)
    } ov;
    __shared__ float b1s[8][8][8];                   // [d][wi][D] 2048 B

    // ---- phase 0: stage bf16 x patch (uint pair loads, clamped tail) ----
    for (int i = t; i < CIN*DDEP*3*5; i += 256) {
        int ci = i / 120, rem = i - ci*120;
        int D  = rem / 15, r2 = rem - D*15;
        int kh = r2 / 5, uc = r2 - kh*5;
        int xc = w0 + uc*2;
        const ushort* row = xb + (((size_t)(bb*CIN + ci)*DDEP + D)*HIN + (h0+kh))*WIN;
        unsigned v;
        if (xc + 1 < WIN) v = *(const unsigned*)&row[xc];
        else { unsigned e = row[95]; v = e | (e << 16); }  // clamp: garbage cols feed only invalid sites
        *(unsigned*)&ov.patchb[ci][D][kh][uc*2] = v;
    }
    __syncthreads();

    // ---- phase 1: im2col (pure ushort packing; no f2bf) ----
    {
        const int site = t >> 2, kg = t & 3;     // site = D*8 + wi
        const int D = site >> 3, wi = site & 7;
        #pragma unroll
        for (int u2 = 0; u2 < 18; ++u2) {
            int k0 = kg*36 + u2*2;
            int ci0 = k0/9, r0 = k0 - ci0*9, kh0 = r0/3, kw0 = r0 - kh0*3;
            int k1 = k0 + 1;
            int ci1 = k1/9, r1 = k1 - ci1*9, kh1 = r1/3, kw1 = r1 - kh1*3;
            unsigned lo = ov.patchb[ci0][D][kh0][wi+kw0];
            unsigned hi = ov.patchb[ci1][D][kh1][wi+kw1];
            *(unsigned*)&a_hi[site][k0] = lo | (hi << 16);
        }
        if (t < 64) {
            #pragma unroll
            for (int kk = KTOT; kk < KTILES*32; kk += 2)
                *(unsigned*)&a_hi[t][kk] = 0u;
        }
    }
    __syncthreads();

    // ---- phase 2: MFMA K-loop ----
    const int wv = t >> 6, lane = t & 63;
    const int m16 = lane & 15, quad = lane >> 4;
    const int Dq  = quad >> 1;      // D parity bit (lane bit5)
    const int wih = quad & 1;       // wi half (lane bit4)
    f32x4 acc[4][4];
    #pragma unroll
    for (int mt = 0; mt < 4; ++mt)
        #pragma unroll
        for (int nt = 0; nt < 4; ++nt)
            acc[mt][nt] = (f32x4){0.f, 0.f, 0.f, 0.f};

    #pragma unroll
    for (int kt = 0; kt < KTILES; ++kt) {
        bf16x8 ah[4];
        #pragma unroll
        for (int mt = 0; mt < 4; ++mt)
            ah[mt] = *(const bf16x8*)&a_hi[mt*16 + m16][kt*32 + quad*8];
        #pragma unroll
        for (int nt = 0; nt < 4; ++nt) {
            size_t off = (((size_t)kt*16 + (wv*4 + nt))*64 + lane)*8;
            bf16x8 bh = *(const bf16x8*)&w_hi[off];
            bf16x8 bl = *(const bf16x8*)&w_lo[off];
            #pragma unroll
            for (int mt = 0; mt < 4; ++mt) {
                acc[mt][nt] = __builtin_amdgcn_mfma_f32_16x16x32_bf16(ah[mt], bh, acc[mt][nt], 0, 0, 0);
                acc[mt][nt] = __builtin_amdgcn_mfma_f32_16x16x32_bf16(ah[mt], bl, acc[mt][nt], 0, 0, 0);
            }
        }
    }

    // ---- phase 3: Gram G_DD'(d,wi) = sum_c u_cD*u_cD' (core VERBATIM r12) ----
    {
        const int c3 = m16 >> 3;
        const int dL = m16 & 7;
        __syncthreads();   // all waves past phase-1 reads before gst reuse
        #pragma unroll
        for (int r = 0; r < 4; ++r) {
            const int rq = r >> 1;          // assigned Dq for this r
            float G36[36];
            #pragma unroll
            for (int j = 0; j < 36; ++j) G36[j] = 0.f;
            #pragma unroll
            for (int nt = 0; nt < 4; ++nt) {
                float u8[8];
                #pragma unroll
                for (int mt = 0; mt < 4; ++mt) {
                    float own = acc[mt][nt][r];
                    float oth = __shfl_xor(own, 32);   // all lanes participate
                    if (Dq == 0) { u8[mt*2]   = own; u8[mt*2+1] = oth; }
                    else         { u8[mt*2+1] = own; u8[mt*2]   = oth; }
                }
                if (Dq == rq) {
                    int idx = 0;
                    #pragma unroll
                    for (int D = 0; D < 8; ++D)
                        #pragma unroll
                        for (int Dp = D; Dp < 8; ++Dp) {
                            G36[idx] += u8[D]*u8[Dp];
                            ++idx;
                        }
                }
            }
            if (Dq == rq) {   // xor-8 partners share Dq; half-wave uniform
                #pragma unroll
                for (int j = 0; j < 36; ++j) G36[j] += __shfl_xor(G36[j], 8);
                if (c3 == 0) {
                    #pragma unroll
                    for (int j = 0; j < 36; ++j) ov.gst[wv][dL*2 + wih][j] = G36[j];
                }
            }
            __syncthreads();
            // cross-wave sum + global write: 16 sites x 36, 144B runs per site
            for (int idx2 = t; idx2 < 16*36; idx2 += 256) {
                int sidx = idx2 / 36, j = idx2 - sidx*36;
                int dd = sidx >> 1, wh = sidx & 1;
                int w = w0 + wh*4 + r;
                if (w < WOUT) {
                    float gv = ov.gst[0][sidx][j] + ov.gst[1][sidx][j]
                             + ov.gst[2][sidx][j] + ov.gst[3][sidx][j];
                    size_t gsite = ((size_t)(bb*DCAP + dd)*HOUT + h0)*WOUT + w;
                    Gm[gsite*36 + j] = gv;
                }
            }
            // r19: iter1-from-G for this r's 16 sites (verbatim gram_route<1>
            // math; g re-summed in the same order as the Gm write -> same bits)
            if (t < 16) {
                const int sdd = t >> 1, swh = t & 1;
                const int sw = w0 + swh*4 + r;
                if (sw < WOUT) {
                    const float inv = 1.0f / (float)(DCAP * HW);
                    float g36[36];
                    #pragma unroll
                    for (int j = 0; j < 36; ++j)
                        g36[j] = ov.gst[0][t][j] + ov.gst[1][t][j]
                               + ov.gst[2][t][j] + ov.gst[3][t][j];
                    float tD[8];
                    #pragma unroll
                    for (int D = 0; D < 8; ++D) tD[D] = 0.f;
                    int idx = 0;
                    #pragma unroll
                    for (int D = 0; D < 8; ++D)
                        #pragma unroll
                        for (int Dp = D; Dp < 8; ++Dp) {
                            float gv = g36[idx]; ++idx;
                            tD[D] += inv * gv;
                            if (Dp != D) tD[Dp] += inv * gv;
                        }
                    float n2 = 0.f;
                    #pragma unroll
                    for (int D = 0; D < 8; ++D) n2 += inv * tD[D];
                    float fac = (n2 / (1.f + n2)) / sqrtf(n2 + EPSQ);
                    #pragma unroll
                    for (int D = 0; D < 8; ++D) b1s[sdd][swh*4 + r][D] = fac * tD[D];
                }
            }
            __syncthreads();   // before next r overwrites gst; b1s visible
        }
    }

    // ---- phase 4: b1 write (r17's proven coalesced float2 form) + Z1 ----
    {
        int Dd = t >> 2, wip = t & 3;
        int D = Dd >> 3, d2 = Dd & 7;   // D = t>>5, uniform per 32-lane group
        int w = w0 + wip*2;
        float ez = 0.f;
        if (w + 1 < WOUT) {
            float2 add;
            add.x = b1s[d2][wip*2][D];
            add.y = b1s[d2][wip*2 + 1][D];
            *(float2*)&bws[((size_t)bb*64 + Dd)*HW + (size_t)h0*WOUT + w] = add;
            ez = expf(add.x) + expf(add.y);   // same values later read as cms
        }
        #pragma unroll
        for (int off = 1; off < 32; off <<= 1) ez += __shfl_xor(ez, off);
        if ((t & 31) == 0)
            Zp1[((size_t)bb*8 + D)*BLK_PER_B + h0*12 + wx] = ez;
    }
}

// ---------------------------------------------------------------------------
// Routing iteration 2 from the Gram matrix (pure streaming; validated r12+).
// r19: Z1 reduce fused into the prologue (Zp1 is 288KB, L2-resident; identical
// deterministic order in every block -> consistent invZ1). Z2 partials -> Zp2
// (separate buffer from Zp1 — blocks still read Zp1 concurrently).
// ---------------------------------------------------------------------------
__global__ __launch_bounds__(256) void gram_route2(
    const float* __restrict__ Gm, float* __restrict__ bws,
    const float* __restrict__ Zp1, float* __restrict__ Zp2)
{
    const int k = blockIdx.x, bb = blockIdx.y;
    const int t = threadIdx.x;

    __shared__ float invZ1[8];
    {
        const int Dg = t >> 5;                       // 32 lanes per D
        const float* p = Zp1 + ((size_t)bb*8 + Dg)*BLK_PER_B;
        float s = 0.f;
        for (int k2 = (t & 31); k2 < BLK_PER_B; k2 += 32) s += p[k2];
        #pragma unroll
        for (int off = 1; off < 32; off <<= 1) s += __shfl_xor(s, off);
        if ((t & 31) == 0) invZ1[Dg] = 1.0f / s;
    }
    __syncthreads();

    const int local = k*256 + t;
    const bool valid = local < VSITES;
    float ez8[8];
    #pragma unroll
    for (int D = 0; D < 8; ++D) ez8[D] = 0.f;
    if (valid) {
        const int d  = local / HW;
        const int r2 = local - d*HW;
        float bv[8], cm[8];
        #pragma unroll
        for (int D = 0; D < 8; ++D) {
            bv[D] = bws[((size_t)(bb*64 + D*8 + d))*HW + r2];
            cm[D] = expf(bv[D]) * invZ1[D];
        }
        float g[36];
        const float4* gp = (const float4*)(Gm + (size_t)(bb*VSITES + local)*36);
        #pragma unroll
        for (int q = 0; q < 9; ++q) {
            float4 v = gp[q];
            g[q*4+0] = v.x; g[q*4+1] = v.y; g[q*4+2] = v.z; g[q*4+3] = v.w;
        }
        float tD[8];
        #pragma unroll
        for (int D = 0; D < 8; ++D) tD[D] = 0.f;
        {
            int idx = 0;
            #pragma unroll
            for (int D = 0; D < 8; ++D)
                #pragma unroll
                for (int Dp = D; Dp < 8; ++Dp) {
                    float gv = g[idx]; ++idx;
                    tD[D] += cm[Dp] * gv;
                    if (Dp != D) tD[Dp] += cm[D] * gv;
                }
        }
        float n2 = 0.f;
        #pragma unroll
        for (int D = 0; D < 8; ++D) n2 += cm[D] * tD[D];
        float fac = (n2 / (1.f + n2)) / sqrtf(n2 + EPSQ);
        #pragma unroll
        for (int D = 0; D < 8; ++D) {
            float nb = bv[D] + fac * tD[D];
            bws[((size_t)(bb*64 + D*8 + d))*HW + r2] = nb;
            ez8[D] = expf(nb);
        }
    }
    // block-reduce 8 per-D sums -> contention-free Zp2 slot
    #pragma unroll
    for (int D = 0; D < 8; ++D)
        #pragma unroll
        for (int off = 1; off < 64; off <<= 1) ez8[D] += __shfl_xor(ez8[D], off);
    __shared__ float ps[4][8];
    if ((t & 63) == 0) {
        #pragma unroll
        for (int D = 0; D < 8; ++D) ps[t >> 6][D] = ez8[D];
    }
    __syncthreads();
    if (t < 8)
        Zp2[((size_t)bb*8 + t)*NBLK2 + k] = ps[0][t] + ps[1][t] + ps[2][t] + ps[3][t];
}

// ---------------------------------------------------------------------------
// Pass C: conv + MODE2 epilogue (s output). Verbatim r17/r18 except the
// invZ prologue now reduces Zp2 directly (70KB, L2-resident).
// ---------------------------------------------------------------------------
__global__ __launch_bounds__(256, 2) void conv_s(
    const ushort* __restrict__ xb,
    const ushort* __restrict__ w_hi, const ushort* __restrict__ w_lo,
    const float* __restrict__ bws, const float* __restrict__ Zp2,
    float* __restrict__ out)
{
    const int t  = threadIdx.x;
    const int wx = blockIdx.x, h0 = blockIdx.y, bb = blockIdx.z;
    const int w0 = wx*8;

    __shared__ __align__(16) ushort a_hi[64][APAD];  // 21504 B
    __shared__ float  cms[64][8];                    // 2048 B
    __shared__ float  invZ[8];
    __shared__ union {                               // 8192 B
        ushort patchb[CIN][DDEP][3][10];             //   phases 0-1 (7680 B)
        float  sout[256][8];                         //   epilogue
    } ov;

    // ---- phase 0: fused Z2 reduce + c-coeffs + bf16 patch ----
    {
        const int Dg = t >> 5;
        const float* p = Zp2 + ((size_t)bb*8 + Dg)*NBLK2;
        float s = 0.f;
        for (int k2 = (t & 31); k2 < NBLK2; k2 += 32) s += p[k2];
        #pragma unroll
        for (int off = 1; off < 32; off <<= 1) s += __shfl_xor(s, off);
        if ((t & 31) == 0) invZ[Dg] = 1.0f / s;
    }
    for (int v = t; v < 512; v += 256) {
        int Dd = v >> 3, wi = v & 7;
        int w = w0 + wi;
        float bv = (w < WOUT) ? bws[((size_t)bb*64 + Dd)*HW + (size_t)h0*WOUT + w] : 0.f;
        cms[Dd][wi] = expf(bv);
    }
    for (int i = t; i < CIN*DDEP*3*5; i += 256) {
        int ci = i / 120, rem = i - ci*120;
        int D  = rem / 15, r2 = rem - D*15;
        int kh = r2 / 5, uc = r2 - kh*5;
        int xc = w0 + uc*2;
        const ushort* row = xb + (((size_t)(bb*CIN + ci)*DDEP + D)*HIN + (h0+kh))*WIN;
        unsigned v;
        if (xc + 1 < WIN) v = *(const unsigned*)&row[xc];
        else { unsigned e = row[95]; v = e | (e << 16); }
        *(unsigned*)&ov.patchb[ci][D][kh][uc*2] = v;
    }
    __syncthreads();

    // ---- phase 1: im2col ----
    {
        const int site = t >> 2, kg = t & 3;
        const int D = site >> 3, wi = site & 7;
        #pragma unroll
        for (int u2 = 0; u2 < 18; ++u2) {
            int k0 = kg*36 + u2*2;
            int ci0 = k0/9, r0 = k0 - ci0*9, kh0 = r0/3, kw0 = r0 - kh0*3;
            int k1 = k0 + 1;
            int ci1 = k1/9, r1 = k1 - ci1*9, kh1 = r1/3, kw1 = r1 - kh1*3;
            unsigned lo = ov.patchb[ci0][D][kh0][wi+kw0];
            unsigned hi = ov.patchb[ci1][D][kh1][wi+kw1];
            *(unsigned*)&a_hi[site][k0] = lo | (hi << 16);
        }
        if (t < 64) {
            #pragma unroll
            for (int kk = KTOT; kk < KTILES*32; kk += 2)
                *(unsigned*)&a_hi[t][kk] = 0u;
        }
    }
    __syncthreads();

    // ---- phase 2: MFMA K-loop ----
    const int wv = t >> 6, lane = t & 63;
    const int m16 = lane & 15, quad = lane >> 4;
    f32x4 acc[4][4];
    #pragma unroll
    for (int mt = 0; mt < 4; ++mt)
        #pragma unroll
        for (int nt = 0; nt < 4; ++nt)
            acc[mt][nt] = (f32x4){0.f, 0.f, 0.f, 0.f};

    #pragma unroll
    for (int kt = 0; kt < KTILES; ++kt) {
        bf16x8 ah[4];
        #pragma unroll
        for (int mt = 0; mt < 4; ++mt)
            ah[mt] = *(const bf16x8*)&a_hi[mt*16 + m16][kt*32 + quad*8];
        #pragma unroll
        for (int nt = 0; nt < 4; ++nt) {
            size_t off = (((size_t)kt*16 + (wv*4 + nt))*64 + lane)*8;
            bf16x8 bh = *(const bf16x8*)&w_hi[off];
            bf16x8 bl = *(const bf16x8*)&w_lo[off];
            #pragma unroll
            for (int mt = 0; mt < 4; ++mt) {
                acc[mt][nt] = __builtin_amdgcn_mfma_f32_16x16x32_bf16(ah[mt], bh, acc[mt][nt], 0, 0, 0);
                acc[mt][nt] = __builtin_amdgcn_mfma_f32_16x16x32_bf16(ah[mt], bl, acc[mt][nt], 0, 0, 0);
            }
        }
    }

    // ---- phase 3: s epilogue (verbatim r7-verified MODE2 path) ----
    const int d   = m16 & 7;
    const int Dq  = quad >> 1;
    const int wih = quad & 1;
    float svv[4][4];
    {
        float cmw[4][4];
        #pragma unroll
        for (int mt = 0; mt < 4; ++mt) {
            int D = mt*2 + Dq;
            float iz = invZ[D];
            #pragma unroll
            for (int r = 0; r < 4; ++r) cmw[mt][r] = cms[D*8 + d][wih*4 + r] * iz;
        }
        #pragma unroll
        for (int nt = 0; nt < 4; ++nt)
            #pragma unroll
            for (int r = 0; r < 4; ++r) {
                float partial = 0.f;
                #pragma unroll
                for (int mt = 0; mt < 4; ++mt) partial += cmw[mt][r]*acc[mt][nt][r];
                partial += __shfl_xor(partial, 32);
                svv[nt][r] = partial;   // uniform in lane bit5
            }
    }
    if (quad < 2) {   // one Dq copy per (wih, m16, nt)
        #pragma unroll
        for (int nt = 0; nt < 4; ++nt) {
            int ch = wv*64 + nt*16 + m16;
            #pragma unroll
            for (int r = 0; r < 4; ++r) ov.sout[ch][wih*4 + r] = svv[nt][r];
        }
    }
    __syncthreads();
    for (int i = t; i < 1024; i += 256) {
        int c2 = i >> 2, wip = i & 3;
        int w = w0 + wip*2;
        if (w + 1 < WOUT) {
            float2 v2 = { ov.sout[c2][wip*2], ov.sout[c2][wip*2 + 1] };
            *(float2*)&out[((size_t)bb*CH + c2)*HW + (size_t)h0*WOUT + w] = v2;
        }
    }
}

// ---------------------------------------------------------------------------
// Workspace (~119.4 MB; ws >= 213 MB proven in r11 — single path):
//   bws 18.1 | Zp1 288KB | Zp2 70KB | wfrags 320KB | xb 18.9 | Gm 81.4
// 4 launches (was 8): prep, conv_g, gram_route2, conv_s.
// ---------------------------------------------------------------------------
extern "C" void kernel_launch(void* const* d_in, const int* in_sizes, int n_in,
                              void* d_out, int out_size, void* d_ws, size_t ws_size,
                              hipStream_t stream)
{
    (void)in_sizes; (void)n_in; (void)out_size; (void)ws_size;
    const float* x     = (const float*)d_in[0];
    const float* wconv = (const float*)d_in[1];
    float* out = (float*)d_out;

    float*  bws  = (float*)d_ws;
    float*  Zp1  = bws + B_ELEMS;            // 64*1128 iter1 partials
    float*  Zp2  = Zp1 + 64*BLK_PER_B;       // 64*277 iter2 partials
    ushort* w_hi = (ushort*)(Zp2 + 64*NBLK2);
    ushort* w_lo = w_hi + WFRAG_ELEMS;
    ushort* xb   = w_lo + WFRAG_ELEMS;       // bf16 x cache
    size_t  base = (size_t)((char*)(xb + XN) - (char*)d_ws);
    size_t  goff = (base + 255) & ~(size_t)255;
    float*  Gm   = (float*)((char*)d_ws + goff);

    const dim3 grid(12, 94, 8);
    prep<<<XBLK + 80, 256, 0, stream>>>(x, xb, wconv, w_hi, w_lo);
    conv_g<<<grid, 256, 0, stream>>>(xb, w_hi, w_lo, bws, Zp1, Gm);
    gram_route2<<<dim3(NBLK2, 8), 256, 0, stream>>>(Gm, bws, Zp1, Zp2);
    conv_s<<<grid, 256, 0, stream>>>(xb, w_hi, w_lo, bws, Zp2, out);
}

// Round 11
// 577.888 us; speedup vs baseline: 1.1159x; 1.1159x over previous
//
#include <hip/hip_runtime.h>
#include <math.h>

#define CIN   16
#define DDEP  8      // conv depth (routing "D")
#define HIN   96
#define WIN   96
#define HOUT  94
#define WOUT  94
#define HW    (HOUT*WOUT)        // 8836
#define CH    256                 // out channels = c*8+d
#define DCAP  8
#define KTOT  (CIN*9)             // 144
#define KTILES 5                  // K padded to 160
#define APAD  168                 // A row stride (bf16 elems)
#define EPSQ  1e-8f

#define B_ELEMS ((size_t)8*DDEP*DCAP*HW)          // 4,524,032 floats
#define WFRAG_ELEMS ((size_t)KTILES*16*64*8)      // 40,960 per half
#define VSITES (DCAP*HW)                          // 70,688 sites per batch
#define NBLK2  277                                // ceil(70688/256)
#define XN ((size_t)8*CIN*DDEP*HIN*WIN)           // 9,437,184 x elems
#define XBLK  9216                                // XN/4/256 exactly
#define G_BYTES ((size_t)8*VSITES*36*4)           // 81,432,576 B

typedef __attribute__((ext_vector_type(8))) short bf16x8;
typedef __attribute__((ext_vector_type(4))) float f32x4;

// explicit RNE float->bf16 bit conversion
__device__ __forceinline__ ushort f2bf(float f) {
    unsigned u = __float_as_uint(f);
    return (ushort)((u + 0x7FFFu + ((u >> 16) & 1u)) >> 16);
}
__device__ __forceinline__ float bf2f(ushort h) {
    return __uint_as_float(((unsigned)h) << 16);
}

// ---------------------------------------------------------------------------
// prep (r19-validated): fused (a) x -> bf16 side-cache (blocks 0..9215) and
// (b) W -> MFMA B-fragment hi/lo split (blocks 9216..9295;
// frag[kt][nt][lane][j] = W[k][n], k = kt*32+(lane>>4)*8+j (0 for k>=144),
// n = nt*16+(lane&15)).
// ---------------------------------------------------------------------------
__global__ __launch_bounds__(256) void prep(
    const float* __restrict__ x, ushort* __restrict__ xb,
    const float* __restrict__ w, ushort* __restrict__ w_hi, ushort* __restrict__ w_lo)
{
    const int bid = blockIdx.x;
    if (bid < XBLK) {
        size_t i = (size_t)bid*256 + threadIdx.x;
        float4 v = ((const float4*)x)[i];
        ushort4 o;
        o.x = f2bf(v.x); o.y = f2bf(v.y); o.z = f2bf(v.z); o.w = f2bf(v.w);
        ((ushort4*)xb)[i] = o;
    } else if (threadIdx.x < 64) {
        const int b2 = bid - XBLK;
        const int nt = b2 & 15, kt = b2 >> 4;
        const int lane = threadIdx.x;
        const int n  = nt*16 + (lane & 15);
        const int kb = kt*32 + (lane >> 4)*8;
        size_t off = (((size_t)kt*16 + nt)*64 + lane)*8;
        for (int j = 0; j < 8; ++j) {
            int k = kb + j;
            float v = (k < KTOT) ? w[(size_t)n*KTOT + k] : 0.f;
            ushort hi = f2bf(v);
            float  r  = v - bf2f(hi);
            ushort lo = f2bf(r);
            w_hi[off + j] = hi; w_lo[off + j] = lo;
        }
    }
}

// ---------------------------------------------------------------------------
// Pass A: conv + Gram write ONLY (VERBATIM r18 — measured 265us, WRITE 79.6MB,
// no spill). r19 lesson: do NOT fuse iter1 into the per-r barrier loop —
// 16-active-thread serial sections on the critical path cost +67us (vs the
// 30us streaming kernel they replaced) and raised bank conflicts 1.5x.
// r13/r14 lesson: do NOT restructure the G36 accumulation (per-r barriers +
// Dq==rq guards bound liveness; all-lane batched rewrite spilled 1.2GB).
// Keep __launch_bounds__(256,2). Spill tripwire: WRITE_SIZE ~79.6MB.
// acc[mt][nt][r]: m = mt*16 + quad*4 + r -> D = mt*2 + (quad>>1),
//                 wi = (quad&1)*4 + r;  ch = wv*64 + nt*16 + m16.
// ---------------------------------------------------------------------------
__global__ __launch_bounds__(256, 2) void conv_g(
    const ushort* __restrict__ xb,
    const ushort* __restrict__ w_hi, const ushort* __restrict__ w_lo,
    float* __restrict__ Gm)
{
    const int t  = threadIdx.x;
    const int wx = blockIdx.x, h0 = blockIdx.y, bb = blockIdx.z;
    const int w0 = wx*8;

    __shared__ __align__(16) ushort a_hi[64][APAD];  // 21504 B (all phases)
    __shared__ union {                               // 9216 B, lifetime-disjoint
        ushort patchb[CIN][DDEP][3][10];             //   phases 0-1 (7680 B)
        float gst[4][16][36];                        //   Gram staging (post-MFMA)
    } ov;

    // ---- phase 0: stage bf16 x patch (uint pair loads, clamped tail) ----
    for (int i = t; i < CIN*DDEP*3*5; i += 256) {
        int ci = i / 120, rem = i - ci*120;
        int D  = rem / 15, r2 = rem - D*15;
        int kh = r2 / 5, uc = r2 - kh*5;
        int xc = w0 + uc*2;
        const ushort* row = xb + (((size_t)(bb*CIN + ci)*DDEP + D)*HIN + (h0+kh))*WIN;
        unsigned v;
        if (xc + 1 < WIN) v = *(const unsigned*)&row[xc];
        else { unsigned e = row[95]; v = e | (e << 16); }  // clamp: garbage cols feed only invalid sites
        *(unsigned*)&ov.patchb[ci][D][kh][uc*2] = v;
    }
    __syncthreads();

    // ---- phase 1: im2col (pure ushort packing; no f2bf) ----
    {
        const int site = t >> 2, kg = t & 3;     // site = D*8 + wi
        const int D = site >> 3, wi = site & 7;
        #pragma unroll
        for (int u2 = 0; u2 < 18; ++u2) {
            int k0 = kg*36 + u2*2;
            int ci0 = k0/9, r0 = k0 - ci0*9, kh0 = r0/3, kw0 = r0 - kh0*3;
            int k1 = k0 + 1;
            int ci1 = k1/9, r1 = k1 - ci1*9, kh1 = r1/3, kw1 = r1 - kh1*3;
            unsigned lo = ov.patchb[ci0][D][kh0][wi+kw0];
            unsigned hi = ov.patchb[ci1][D][kh1][wi+kw1];
            *(unsigned*)&a_hi[site][k0] = lo | (hi << 16);
        }
        if (t < 64) {
            #pragma unroll
            for (int kk = KTOT; kk < KTILES*32; kk += 2)
                *(unsigned*)&a_hi[t][kk] = 0u;
        }
    }
    __syncthreads();

    // ---- phase 2: MFMA K-loop ----
    const int wv = t >> 6, lane = t & 63;
    const int m16 = lane & 15, quad = lane >> 4;
    const int Dq  = quad >> 1;      // D parity bit (lane bit5)
    const int wih = quad & 1;       // wi half (lane bit4)
    f32x4 acc[4][4];
    #pragma unroll
    for (int mt = 0; mt < 4; ++mt)
        #pragma unroll
        for (int nt = 0; nt < 4; ++nt)
            acc[mt][nt] = (f32x4){0.f, 0.f, 0.f, 0.f};

    #pragma unroll
    for (int kt = 0; kt < KTILES; ++kt) {
        bf16x8 ah[4];
        #pragma unroll
        for (int mt = 0; mt < 4; ++mt)
            ah[mt] = *(const bf16x8*)&a_hi[mt*16 + m16][kt*32 + quad*8];
        #pragma unroll
        for (int nt = 0; nt < 4; ++nt) {
            size_t off = (((size_t)kt*16 + (wv*4 + nt))*64 + lane)*8;
            bf16x8 bh = *(const bf16x8*)&w_hi[off];
            bf16x8 bl = *(const bf16x8*)&w_lo[off];
            #pragma unroll
            for (int mt = 0; mt < 4; ++mt) {
                acc[mt][nt] = __builtin_amdgcn_mfma_f32_16x16x32_bf16(ah[mt], bh, acc[mt][nt], 0, 0, 0);
                acc[mt][nt] = __builtin_amdgcn_mfma_f32_16x16x32_bf16(ah[mt], bl, acc[mt][nt], 0, 0, 0);
            }
        }
    }

    // ---- phase 3: Gram G_DD'(d,wi) = sum_c u_cD*u_cD' (VERBATIM r12) ----
    {
        const int c3 = m16 >> 3;
        const int dL = m16 & 7;
        __syncthreads();   // all waves past phase-1 reads before gst reuse
        #pragma unroll
        for (int r = 0; r < 4; ++r) {
            const int rq = r >> 1;          // assigned Dq for this r
            float G36[36];
            #pragma unroll
            for (int j = 0; j < 36; ++j) G36[j] = 0.f;
            #pragma unroll
            for (int nt = 0; nt < 4; ++nt) {
                float u8[8];
                #pragma unroll
                for (int mt = 0; mt < 4; ++mt) {
                    float own = acc[mt][nt][r];
                    float oth = __shfl_xor(own, 32);   // all lanes participate
                    if (Dq == 0) { u8[mt*2]   = own; u8[mt*2+1] = oth; }
                    else         { u8[mt*2+1] = own; u8[mt*2]   = oth; }
                }
                if (Dq == rq) {
                    int idx = 0;
                    #pragma unroll
                    for (int D = 0; D < 8; ++D)
                        #pragma unroll
                        for (int Dp = D; Dp < 8; ++Dp) {
                            G36[idx] += u8[D]*u8[Dp];
                            ++idx;
                        }
                }
            }
            if (Dq == rq) {   // xor-8 partners share Dq; half-wave uniform
                #pragma unroll
                for (int j = 0; j < 36; ++j) G36[j] += __shfl_xor(G36[j], 8);
                if (c3 == 0) {
                    #pragma unroll
                    for (int j = 0; j < 36; ++j) ov.gst[wv][dL*2 + wih][j] = G36[j];
                }
            }
            __syncthreads();
            // cross-wave sum + global write: 16 sites x 36, 144B runs per site
            for (int idx2 = t; idx2 < 16*36; idx2 += 256) {
                int sidx = idx2 / 36, j = idx2 - sidx*36;
                int dd = sidx >> 1, wh = sidx & 1;
                int w = w0 + wh*4 + r;
                if (w < WOUT) {
                    float gv = ov.gst[0][sidx][j] + ov.gst[1][sidx][j]
                             + ov.gst[2][sidx][j] + ov.gst[3][sidx][j];
                    size_t gsite = ((size_t)(bb*DCAP + dd)*HOUT + h0)*WOUT + w;
                    Gm[gsite*36 + j] = gv;
                }
            }
            __syncthreads();   // before next r overwrites gst
        }
    }
}

// ---------------------------------------------------------------------------
// Routing iteration 1 from the Gram matrix (pure streaming; validated
// r13/r14/r18). cm uniform (b0=0): b1 = fac*(G cm); Z1 partials -> Zp1.
// ---------------------------------------------------------------------------
__global__ __launch_bounds__(256) void gram_route1(
    const float* __restrict__ Gm, float* __restrict__ bws,
    float* __restrict__ Zp1)
{
    const int k = blockIdx.x, bb = blockIdx.y;
    const int t = threadIdx.x;
    const int local = k*256 + t;
    const bool valid = local < VSITES;
    float ez8[8];
    #pragma unroll
    for (int D = 0; D < 8; ++D) ez8[D] = 0.f;
    if (valid) {
        const int d  = local / HW;
        const int r2 = local - d*HW;
        const float inv = 1.0f / (float)(DCAP * HW);
        float g[36];
        const float4* gp = (const float4*)(Gm + (size_t)(bb*VSITES + local)*36);
        #pragma unroll
        for (int q = 0; q < 9; ++q) {
            float4 v = gp[q];
            g[q*4+0] = v.x; g[q*4+1] = v.y; g[q*4+2] = v.z; g[q*4+3] = v.w;
        }
        float tD[8];
        #pragma unroll
        for (int D = 0; D < 8; ++D) tD[D] = 0.f;
        {
            int idx = 0;
            #pragma unroll
            for (int D = 0; D < 8; ++D)
                #pragma unroll
                for (int Dp = D; Dp < 8; ++Dp) {
                    float gv = g[idx]; ++idx;
                    tD[D] += inv * gv;
                    if (Dp != D) tD[Dp] += inv * gv;
                }
        }
        float n2 = 0.f;
        #pragma unroll
        for (int D = 0; D < 8; ++D) n2 += inv * tD[D];
        float fac = (n2 / (1.f + n2)) / sqrtf(n2 + EPSQ);
        #pragma unroll
        for (int D = 0; D < 8; ++D) {
            float nb = fac * tD[D];
            bws[((size_t)(bb*64 + D*8 + d))*HW + r2] = nb;
            ez8[D] = expf(nb);
        }
    }
    // block-reduce 8 per-D sums -> contention-free Zp1 slot
    #pragma unroll
    for (int D = 0; D < 8; ++D)
        #pragma unroll
        for (int off = 1; off < 64; off <<= 1) ez8[D] += __shfl_xor(ez8[D], off);
    __shared__ float ps[4][8];
    if ((t & 63) == 0) {
        #pragma unroll
        for (int D = 0; D < 8; ++D) ps[t >> 6][D] = ez8[D];
    }
    __syncthreads();
    if (t < 8)
        Zp1[((size_t)bb*8 + t)*NBLK2 + k] = ps[0][t] + ps[1][t] + ps[2][t] + ps[3][t];
}

// ---------------------------------------------------------------------------
// Routing iteration 2 from the Gram matrix (r19-validated form): Z1 reduce
// fused into the prologue (Zp1 70KB, L2-resident; deterministic order ->
// identical invZ1 in every block). Z2 partials -> Zp2.
// ---------------------------------------------------------------------------
__global__ __launch_bounds__(256) void gram_route2(
    const float* __restrict__ Gm, float* __restrict__ bws,
    const float* __restrict__ Zp1, float* __restrict__ Zp2)
{
    const int k = blockIdx.x, bb = blockIdx.y;
    const int t = threadIdx.x;

    __shared__ float invZ1[8];
    {
        const int Dg = t >> 5;                       // 32 lanes per D
        const float* p = Zp1 + ((size_t)bb*8 + Dg)*NBLK2;
        float s = 0.f;
        for (int k2 = (t & 31); k2 < NBLK2; k2 += 32) s += p[k2];
        #pragma unroll
        for (int off = 1; off < 32; off <<= 1) s += __shfl_xor(s, off);
        if ((t & 31) == 0) invZ1[Dg] = 1.0f / s;
    }
    __syncthreads();

    const int local = k*256 + t;
    const bool valid = local < VSITES;
    float ez8[8];
    #pragma unroll
    for (int D = 0; D < 8; ++D) ez8[D] = 0.f;
    if (valid) {
        const int d  = local / HW;
        const int r2 = local - d*HW;
        float bv[8], cm[8];
        #pragma unroll
        for (int D = 0; D < 8; ++D) {
            bv[D] = bws[((size_t)(bb*64 + D*8 + d))*HW + r2];
            cm[D] = expf(bv[D]) * invZ1[D];
        }
        float g[36];
        const float4* gp = (const float4*)(Gm + (size_t)(bb*VSITES + local)*36);
        #pragma unroll
        for (int q = 0; q < 9; ++q) {
            float4 v = gp[q];
            g[q*4+0] = v.x; g[q*4+1] = v.y; g[q*4+2] = v.z; g[q*4+3] = v.w;
        }
        float tD[8];
        #pragma unroll
        for (int D = 0; D < 8; ++D) tD[D] = 0.f;
        {
            int idx = 0;
            #pragma unroll
            for (int D = 0; D < 8; ++D)
                #pragma unroll
                for (int Dp = D; Dp < 8; ++Dp) {
                    float gv = g[idx]; ++idx;
                    tD[D] += cm[Dp] * gv;
                    if (Dp != D) tD[Dp] += cm[D] * gv;
                }
        }
        float n2 = 0.f;
        #pragma unroll
        for (int D = 0; D < 8; ++D) n2 += cm[D] * tD[D];
        float fac = (n2 / (1.f + n2)) / sqrtf(n2 + EPSQ);
        #pragma unroll
        for (int D = 0; D < 8; ++D) {
            float nb = bv[D] + fac * tD[D];
            bws[((size_t)(bb*64 + D*8 + d))*HW + r2] = nb;
            ez8[D] = expf(nb);
        }
    }
    // block-reduce 8 per-D sums -> contention-free Zp2 slot
    #pragma unroll
    for (int D = 0; D < 8; ++D)
        #pragma unroll
        for (int off = 1; off < 64; off <<= 1) ez8[D] += __shfl_xor(ez8[D], off);
    __shared__ float ps[4][8];
    if ((t & 63) == 0) {
        #pragma unroll
        for (int D = 0; D < 8; ++D) ps[t >> 6][D] = ez8[D];
    }
    __syncthreads();
    if (t < 8)
        Zp2[((size_t)bb*8 + t)*NBLK2 + k] = ps[0][t] + ps[1][t] + ps[2][t] + ps[3][t];
}

// ---------------------------------------------------------------------------
// Pass C: conv + MODE2 epilogue (s output). r19-validated form (fused Z2
// reduce in prologue; rest verbatim r17/r18).
// ---------------------------------------------------------------------------
__global__ __launch_bounds__(256, 2) void conv_s(
    const ushort* __restrict__ xb,
    const ushort* __restrict__ w_hi, const ushort* __restrict__ w_lo,
    const float* __restrict__ bws, const float* __restrict__ Zp2,
    float* __restrict__ out)
{
    const int t  = threadIdx.x;
    const int wx = blockIdx.x, h0 = blockIdx.y, bb = blockIdx.z;
    const int w0 = wx*8;

    __shared__ __align__(16) ushort a_hi[64][APAD];  // 21504 B
    __shared__ float  cms[64][8];                    // 2048 B
    __shared__ float  invZ[8];
    __shared__ union {                               // 8192 B
        ushort patchb[CIN][DDEP][3][10];             //   phases 0-1 (7680 B)
        float  sout[256][8];                         //   epilogue
    } ov;

    // ---- phase 0: fused Z2 reduce + c-coeffs + bf16 patch ----
    {
        const int Dg = t >> 5;
        const float* p = Zp2 + ((size_t)bb*8 + Dg)*NBLK2;
        float s = 0.f;
        for (int k2 = (t & 31); k2 < NBLK2; k2 += 32) s += p[k2];
        #pragma unroll
        for (int off = 1; off < 32; off <<= 1) s += __shfl_xor(s, off);
        if ((t & 31) == 0) invZ[Dg] = 1.0f / s;
    }
    for (int v = t; v < 512; v += 256) {
        int Dd = v >> 3, wi = v & 7;
        int w = w0 + wi;
        float bv = (w < WOUT) ? bws[((size_t)bb*64 + Dd)*HW + (size_t)h0*WOUT + w] : 0.f;
        cms[Dd][wi] = expf(bv);
    }
    for (int i = t; i < CIN*DDEP*3*5; i += 256) {
        int ci = i / 120, rem = i - ci*120;
        int D  = rem / 15, r2 = rem - D*15;
        int kh = r2 / 5, uc = r2 - kh*5;
        int xc = w0 + uc*2;
        const ushort* row = xb + (((size_t)(bb*CIN + ci)*DDEP + D)*HIN + (h0+kh))*WIN;
        unsigned v;
        if (xc + 1 < WIN) v = *(const unsigned*)&row[xc];
        else { unsigned e = row[95]; v = e | (e << 16); }
        *(unsigned*)&ov.patchb[ci][D][kh][uc*2] = v;
    }
    __syncthreads();

    // ---- phase 1: im2col ----
    {
        const int site = t >> 2, kg = t & 3;
        const int D = site >> 3, wi = site & 7;
        #pragma unroll
        for (int u2 = 0; u2 < 18; ++u2) {
            int k0 = kg*36 + u2*2;
            int ci0 = k0/9, r0 = k0 - ci0*9, kh0 = r0/3, kw0 = r0 - kh0*3;
            int k1 = k0 + 1;
            int ci1 = k1/9, r1 = k1 - ci1*9, kh1 = r1/3, kw1 = r1 - kh1*3;
            unsigned lo = ov.patchb[ci0][D][kh0][wi+kw0];
            unsigned hi = ov.patchb[ci1][D][kh1][wi+kw1];
            *(unsigned*)&a_hi[site][k0] = lo | (hi << 16);
        }
        if (t < 64) {
            #pragma unroll
            for (int kk = KTOT; kk < KTILES*32; kk += 2)
                *(unsigned*)&a_hi[t][kk] = 0u;
        }
    }
    __syncthreads();

    // ---- phase 2: MFMA K-loop ----
    const int wv = t >> 6, lane = t & 63;
    const int m16 = lane & 15, quad = lane >> 4;
    f32x4 acc[4][4];
    #pragma unroll
    for (int mt = 0; mt < 4; ++mt)
        #pragma unroll
        for (int nt = 0; nt < 4; ++nt)
            acc[mt][nt] = (f32x4){0.f, 0.f, 0.f, 0.f};

    #pragma unroll
    for (int kt = 0; kt < KTILES; ++kt) {
        bf16x8 ah[4];
        #pragma unroll
        for (int mt = 0; mt < 4; ++mt)
            ah[mt] = *(const bf16x8*)&a_hi[mt*16 + m16][kt*32 + quad*8];
        #pragma unroll
        for (int nt = 0; nt < 4; ++nt) {
            size_t off = (((size_t)kt*16 + (wv*4 + nt))*64 + lane)*8;
            bf16x8 bh = *(const bf16x8*)&w_hi[off];
            bf16x8 bl = *(const bf16x8*)&w_lo[off];
            #pragma unroll
            for (int mt = 0; mt < 4; ++mt) {
                acc[mt][nt] = __builtin_amdgcn_mfma_f32_16x16x32_bf16(ah[mt], bh, acc[mt][nt], 0, 0, 0);
                acc[mt][nt] = __builtin_amdgcn_mfma_f32_16x16x32_bf16(ah[mt], bl, acc[mt][nt], 0, 0, 0);
            }
        }
    }

    // ---- phase 3: s epilogue (verbatim r7-verified MODE2 path) ----
    const int d   = m16 & 7;
    const int Dq  = quad >> 1;
    const int wih = quad & 1;
    float svv[4][4];
    {
        float cmw[4][4];
        #pragma unroll
        for (int mt = 0; mt < 4; ++mt) {
            int D = mt*2 + Dq;
            float iz = invZ[D];
            #pragma unroll
            for (int r = 0; r < 4; ++r) cmw[mt][r] = cms[D*8 + d][wih*4 + r] * iz;
        }
        #pragma unroll
        for (int nt = 0; nt < 4; ++nt)
            #pragma unroll
            for (int r = 0; r < 4; ++r) {
                float partial = 0.f;
                #pragma unroll
                for (int mt = 0; mt < 4; ++mt) partial += cmw[mt][r]*acc[mt][nt][r];
                partial += __shfl_xor(partial, 32);
                svv[nt][r] = partial;   // uniform in lane bit5
            }
    }
    if (quad < 2) {   // one Dq copy per (wih, m16, nt)
        #pragma unroll
        for (int nt = 0; nt < 4; ++nt) {
            int ch = wv*64 + nt*16 + m16;
            #pragma unroll
            for (int r = 0; r < 4; ++r) ov.sout[ch][wih*4 + r] = svv[nt][r];
        }
    }
    __syncthreads();
    for (int i = t; i < 1024; i += 256) {
        int c2 = i >> 2, wip = i & 3;
        int w = w0 + wip*2;
        if (w + 1 < WOUT) {
            float2 v2 = { ov.sout[c2][wip*2], ov.sout[c2][wip*2 + 1] };
            *(float2*)&out[((size_t)bb*CH + c2)*HW + (size_t)h0*WOUT + w] = v2;
        }
    }
}

// ---------------------------------------------------------------------------
// Workspace (~119 MB; ws >= 213 MB proven in r11 — single path):
//   bws 18.1 | Zp1 70KB | Zp2 70KB | wfrags 320KB | xb 18.9 | Gm 81.4
// 5 launches: prep, conv_g, gram_route1, gram_route2, conv_s.
// ---------------------------------------------------------------------------
extern "C" void kernel_launch(void* const* d_in, const int* in_sizes, int n_in,
                              void* d_out, int out_size, void* d_ws, size_t ws_size,
                              hipStream_t stream)
{
    (void)in_sizes; (void)n_in; (void)out_size; (void)ws_size;
    const float* x     = (const float*)d_in[0];
    const float* wconv = (const float*)d_in[1];
    float* out = (float*)d_out;

    float*  bws  = (float*)d_ws;
    float*  Zp1  = bws + B_ELEMS;            // 64*NBLK2 iter1 partials
    float*  Zp2  = Zp1 + 64*NBLK2;           // 64*NBLK2 iter2 partials
    ushort* w_hi = (ushort*)(Zp2 + 64*NBLK2);
    ushort* w_lo = w_hi + WFRAG_ELEMS;
    ushort* xb   = w_lo + WFRAG_ELEMS;       // bf16 x cache
    size_t  base = (size_t)((char*)(xb + XN) - (char*)d_ws);
    size_t  goff = (base + 255) & ~(size_t)255;
    float*  Gm   = (float*)((char*)d_ws + goff);

    const dim3 grid(12, 94, 8);
    prep<<<XBLK + 80, 256, 0, stream>>>(x, xb, wconv, w_hi, w_lo);
    conv_g<<<grid, 256, 0, stream>>>(xb, w_hi, w_lo, Gm);
    gram_route1<<<dim3(NBLK2, 8), 256, 0, stream>>>(Gm, bws, Zp1);
    gram_route2<<<dim3(NBLK2, 8), 256, 0, stream>>>(Gm, bws, Zp1, Zp2);
    conv_s<<<grid, 256, 0, stream>>>(xb, w_hi, w_lo, bws, Zp2, out);
}